// Round 2
// baseline (6000.219 us; speedup 1.0000x reference)
//
#include <hip/hip_runtime.h>

// ---------------------------------------------------------------------------
// Encoder_conv: emb (1x1 conv) -> 3x { multi-tap K=2 convs summed -> LSTM scan
// with per-step attention gating }.
// B=32, W=512, H=256, 4H=1024, NINP=128, K=2, NLAYERS=3.
//
// Round 2: fix rec_kernel register spill.
//  - __launch_bounds__(1024,4): 1 block/CU, VGPR cap 128.
//  - rw row split per thread (128 packed-f16 dwords):
//      d   0..99  -> VGPRs (100 dwords)
//      d 100..111 -> LDS, stride 12 dwords (48B, 16B-aligned, 3x ds_read_b128)
//      d 112..127 -> global, chunk-major [c][o][4] -> 4x coalesced dwordx4/step
// ---------------------------------------------------------------------------

typedef _Float16 h2 __attribute__((ext_vector_type(2)));

static __device__ __forceinline__ float fdot2(unsigned a, unsigned b, float c) {
#if __has_builtin(__builtin_amdgcn_fdot2)
  return __builtin_amdgcn_fdot2(__builtin_bit_cast(h2, a),
                                __builtin_bit_cast(h2, b), c, false);
#else
  h2 x = __builtin_bit_cast(h2, a), y = __builtin_bit_cast(h2, b);
  return c + (float)x[0] * (float)y[0] + (float)x[1] * (float)y[1];
#endif
}

static __device__ __forceinline__ unsigned short f16b(float v) {
  _Float16 h = (_Float16)v;
  return __builtin_bit_cast(unsigned short, h);
}

static __device__ __forceinline__ float sigm(float x) {
  return 1.0f / (1.0f + __expf(-x));
}
static __device__ __forceinline__ float tanh_(float x) {
  return 1.0f - 2.0f / (1.0f + __expf(2.0f * x));
}

// Packs rec_w into per-layer blocks of 128*1024 dwords:
//  d <112 : [d][o]           (column-major, coalesced init load)
//  d>=112 : chunk-major      base 112*1024 + (c>>2)*4096 + o*4 + (c&3), c=d-112
__global__ __launch_bounds__(256) void prep_rw(const float* __restrict__ rw,
                                               unsigned* __restrict__ rwp) {
  int idx = blockIdx.x * 256 + threadIdx.x;
  if (idx >= 3 * 128 * 1024) return;
  int o = idx & 1023, d = (idx >> 10) & 127, l = idx >> 17;
  const float* src = rw + (l * 1024 + o) * 256 + 2 * d;
  unsigned v = (unsigned)f16b(src[0]) | ((unsigned)f16b(src[1]) << 16);
  int dst;
  if (d < 112) {
    dst = l * 131072 + d * 1024 + o;
  } else {
    int c = d - 112;
    dst = l * 131072 + 114688 + (c >> 2) * 4096 + o * 4 + (c & 3);
  }
  rwp[dst] = v;
}

// cwp[jj][o][k][d] = pack(f16(conv_w[jj][o][2d][k]), f16(conv_w[jj][o][2d+1][k]))
__global__ __launch_bounds__(256) void prep_cw(const float* __restrict__ cw,
                                               unsigned* __restrict__ cwp) {
  int idx = blockIdx.x * 256 + threadIdx.x;
  if (idx >= 6 * 1024 * 2 * 128) return;
  int d = idx & 127, k = (idx >> 7) & 1, o = (idx >> 8) & 1023, jj = idx >> 18;
  const float* src = cw + ((jj * 1024 + o) * 256 + 2 * d) * 2 + k;
  unsigned v = (unsigned)f16b(src[0]) | ((unsigned)f16b(src[2]) << 16);
  cwp[idx] = v;
}

// x0[b,w,h] = sum_c emb_w[h,c]*input[b,c,w] + emb_b[h]; store f16 + out tail.
__global__ __launch_bounds__(256) void emb_kernel(
    const float* __restrict__ inp, const float* __restrict__ ew,
    const float* __restrict__ eb, unsigned short* __restrict__ x0f,
    float* __restrict__ out) {
  __shared__ float xt[32][65];
  __shared__ float wt[64][33];
  int b = blockIdx.z, w0 = blockIdx.x * 64, h0 = blockIdx.y * 64;
  int tid = threadIdx.x, tx = tid & 15, ty = tid >> 4;
  float acc[4][4] = {};
  for (int c0 = 0; c0 < 128; c0 += 32) {
    __syncthreads();
#pragma unroll
    for (int i = 0; i < 8; i++) {
      int f = i * 256 + tid, c = f >> 6, wl = f & 63;
      xt[c][wl] = inp[(b * 128 + c0 + c) * 512 + w0 + wl];
    }
#pragma unroll
    for (int i = 0; i < 8; i++) {
      int f = i * 256 + tid, h = f >> 5, c = f & 31;
      wt[h][c] = ew[(h0 + h) * 128 + c0 + c];
    }
    __syncthreads();
#pragma unroll
    for (int c = 0; c < 32; c++) {
      float xv[4], wv[4];
#pragma unroll
      for (int q = 0; q < 4; q++) xv[q] = xt[c][ty * 4 + q];
#pragma unroll
      for (int p = 0; p < 4; p++) wv[p] = wt[tx * 4 + p][c];
#pragma unroll
      for (int q = 0; q < 4; q++)
#pragma unroll
        for (int p = 0; p < 4; p++) acc[q][p] += xv[q] * wv[p];
    }
  }
#pragma unroll
  for (int q = 0; q < 4; q++) {
    int w = w0 + ty * 4 + q;
#pragma unroll
    for (int p = 0; p < 4; p++) {
      int h = h0 + tx * 4 + p;
      float v = acc[q][p] + eb[h];
      x0f[(b * 512 + w) * 256 + h] = f16b(v);
      if (w >= 510) out[(b * 256 + h) * 2 + (w - 510)] = v;  // x[0] tail
    }
  }
}

// ig[b,w,o] = sum_j sum_{i,k} xpad_j[b,w-1+k,i] * cw[off+j][o,i,k] + biases
__global__ __launch_bounds__(256) void conv_kernel(
    const unsigned short* __restrict__ xf, const unsigned* __restrict__ cwp,
    const float* __restrict__ cb, const float* __restrict__ hidden,
    unsigned short* __restrict__ igf, int l, int off) {
  __shared__ __align__(16) unsigned xs[65][20];    // [pad-col][dw16], stride 20
  __shared__ __align__(16) unsigned wsm[2][16][66];// [k][dw16][o], pad 66
  int b = blockIdx.z, w0 = blockIdx.x * 64, o0 = blockIdx.y * 64;
  int tid = threadIdx.x, tx = tid & 15, ty = tid >> 4;
  float acc[4][4] = {};
  int nl = l + 1;
  for (int j = 0; j < nl; j++) {
    const unsigned* xj = (const unsigned*)(xf + j * 4194304 + b * 512 * 256);
    const unsigned* cwj = cwp + (off + j) * 262144;
    for (int c0 = 0; c0 < 256; c0 += 32) {
      int d0 = c0 >> 1;
      __syncthreads();
#pragma unroll
      for (int i = 0; i < 5; i++) {
        int f = i * 256 + tid;
        if (f < 1040) {
          int col = f >> 4, dw = f & 15;
          int w = w0 - 1 + col;
          unsigned v;
          if (w >= 0) {
            v = xj[w * 128 + d0 + dw];
          } else {  // left pad: hidden[j][b][i][1]
            const float* hp = hidden + ((j * 32 + b) * 256 + 2 * (d0 + dw)) * 2 + 1;
            v = (unsigned)f16b(hp[0]) | ((unsigned)f16b(hp[2]) << 16);
          }
          xs[col][dw] = v;
        }
      }
#pragma unroll
      for (int i = 0; i < 8; i++) {
        int f = i * 256 + tid;
        int oo = f >> 5, k = (f >> 4) & 1, dw = f & 15;
        wsm[k][dw][oo] = cwj[(o0 + oo) * 256 + k * 128 + d0 + dw];
      }
      __syncthreads();
#pragma unroll
      for (int g = 0; g < 4; g++) {
        uint4 xv[5];
#pragma unroll
        for (int q = 0; q < 5; q++)
          xv[q] = *(const uint4*)&xs[ty * 4 + q][g * 4];
#pragma unroll
        for (int p = 0; p < 4; p++) {
          unsigned wv0[4], wv1[4];
#pragma unroll
          for (int r = 0; r < 4; r++) {
            wv0[r] = wsm[0][g * 4 + r][tx * 4 + p];
            wv1[r] = wsm[1][g * 4 + r][tx * 4 + p];
          }
#pragma unroll
          for (int q = 0; q < 4; q++) {
            float a = acc[q][p];
            a = fdot2(wv0[0], xv[q].x, a);
            a = fdot2(wv0[1], xv[q].y, a);
            a = fdot2(wv0[2], xv[q].z, a);
            a = fdot2(wv0[3], xv[q].w, a);
            a = fdot2(wv1[0], xv[q + 1].x, a);
            a = fdot2(wv1[1], xv[q + 1].y, a);
            a = fdot2(wv1[2], xv[q + 1].z, a);
            a = fdot2(wv1[3], xv[q + 1].w, a);
            acc[q][p] = a;
          }
        }
      }
    }
  }
#pragma unroll
  for (int p = 0; p < 4; p++) {
    int o = o0 + tx * 4 + p;
    float bias = 0.f;
    for (int j = 0; j < nl; j++) bias += cb[(off + j) * 1024 + o];
#pragma unroll
    for (int q = 0; q < 4; q++) {
      int w = w0 + ty * 4 + q;
      igf[(b * 512 + w) * 1024 + o] = f16b(acc[q][p] + bias);
    }
  }
}

// One WG per batch; thread o owns gate row o. 512 sequential steps.
__global__ __launch_bounds__(1024, 4) void rec_kernel(
    const _Float16* __restrict__ igf, const unsigned* __restrict__ rwp_l,
    const float* __restrict__ rb, const float* __restrict__ aw,
    const float* __restrict__ hidden, const float* __restrict__ context,
    int l, unsigned short* __restrict__ xnext, float* __restrict__ out) {
  __shared__ __align__(16) unsigned rw_lds[1024 * 12];  // 48 KB
  __shared__ __align__(16) unsigned short hx_half[256]; // hx as f16
  __shared__ __align__(16) _Float16 gates[1024];
  __shared__ float red[4];
  int b = blockIdx.x, o = threadIdx.x;

  unsigned rwreg[100];
#pragma unroll
  for (int d = 0; d < 100; d++) rwreg[d] = rwp_l[(d << 10) + o];
#pragma unroll
  for (int i = 0; i < 12; i++) rw_lds[o * 12 + i] = rwp_l[((100 + i) << 10) + o];

  const uint4* gC = (const uint4*)(rwp_l + (112 << 10));  // [4][1024] uint4

  float rbv = rb[o];
  float cx = 0.f, awj = 0.f;
  if (o < 256) {
    awj = aw[o];
    float h0 = hidden[(((l + 1) * 32 + b) * 256 + o) * 2 + 1];
    cx = context[((l * 32 + b) * 256 + o) * 2 + 1];
    hx_half[o] = f16b(h0);
  }
  __syncthreads();

  const _Float16* igp = igf + (b * 512) * 1024 + o;
  const uint4* rl = (const uint4*)&rw_lds[o * 12];

  for (int t = 0; t < 512; t++) {
    float gin = (float)igp[t * 1024];       // issued early, used at the end
    uint4 g0 = gC[o];                       // prefetch 2 of 4 global chunks
    uint4 g1 = gC[1024 + o];

    float acc0 = rbv, acc1 = 0.f;
    const uint4* hq4 = (const uint4*)hx_half;
#pragma unroll
    for (int q = 0; q < 25; q++) {
      uint4 h = hq4[q];
      if (q & 1) {
        acc1 = fdot2(rwreg[4 * q + 0], h.x, acc1);
        acc1 = fdot2(rwreg[4 * q + 1], h.y, acc1);
        acc1 = fdot2(rwreg[4 * q + 2], h.z, acc1);
        acc1 = fdot2(rwreg[4 * q + 3], h.w, acc1);
      } else {
        acc0 = fdot2(rwreg[4 * q + 0], h.x, acc0);
        acc0 = fdot2(rwreg[4 * q + 1], h.y, acc0);
        acc0 = fdot2(rwreg[4 * q + 2], h.z, acc0);
        acc0 = fdot2(rwreg[4 * q + 3], h.w, acc0);
      }
    }
    uint4 g2 = gC[2048 + o];
    uint4 g3 = gC[3072 + o];
    // LDS-resident weight chunks (hx dwords 100..111)
#pragma unroll
    for (int c = 0; c < 3; c++) {
      uint4 wv = rl[c];
      uint4 h = hq4[25 + c];
      if (c & 1) {
        acc1 = fdot2(wv.x, h.x, acc1);
        acc1 = fdot2(wv.y, h.y, acc1);
        acc1 = fdot2(wv.z, h.z, acc1);
        acc1 = fdot2(wv.w, h.w, acc1);
      } else {
        acc0 = fdot2(wv.x, h.x, acc0);
        acc0 = fdot2(wv.y, h.y, acc0);
        acc0 = fdot2(wv.z, h.z, acc0);
        acc0 = fdot2(wv.w, h.w, acc0);
      }
    }
    // Global-resident weight chunks (hx dwords 112..127)
    {
      uint4 h = hq4[28];
      acc0 = fdot2(g0.x, h.x, acc0);
      acc0 = fdot2(g0.y, h.y, acc0);
      acc0 = fdot2(g0.z, h.z, acc0);
      acc0 = fdot2(g0.w, h.w, acc0);
      h = hq4[29];
      acc1 = fdot2(g1.x, h.x, acc1);
      acc1 = fdot2(g1.y, h.y, acc1);
      acc1 = fdot2(g1.z, h.z, acc1);
      acc1 = fdot2(g1.w, h.w, acc1);
      h = hq4[30];
      acc0 = fdot2(g2.x, h.x, acc0);
      acc0 = fdot2(g2.y, h.y, acc0);
      acc0 = fdot2(g2.z, h.z, acc0);
      acc0 = fdot2(g2.w, h.w, acc0);
      h = hq4[31];
      acc1 = fdot2(g3.x, h.x, acc1);
      acc1 = fdot2(g3.y, h.y, acc1);
      acc1 = fdot2(g3.z, h.z, acc1);
      acc1 = fdot2(g3.w, h.w, acc1);
    }
    gates[o] = (_Float16)(acc0 + acc1 + gin);
    __syncthreads();

    float h_val = 0.f;
    if (o < 256) {
      float g_i = (float)gates[o];
      float g_f = (float)gates[256 + o];
      float g_c = (float)gates[512 + o];
      float g_o = (float)gates[768 + o];
      float si = sigm(g_i), sf = sigm(g_f), tc = tanh_(g_c), so = sigm(g_o);
      cx = sf * cx + si * tc;
      h_val = so * tanh_(cx);
      float part = h_val * awj;
#pragma unroll
      for (int s = 32; s > 0; s >>= 1) part += __shfl_xor(part, s);
      if ((o & 63) == 0) red[o >> 6] = part;
    }
    __syncthreads();
    if (o < 256) {
      float a_ = sigm(red[0] + red[1] + red[2] + red[3]);
      float hg = (t < 511) ? h_val * a_ : h_val;
      hx_half[o] = f16b(hg);
      xnext[(b * 512 + t) * 256 + o] = f16b(hg);
      if (t >= 510) {
        out[(((l + 1) * 32 + b) * 256 + o) * 2 + (t - 510)] = hg;          // x tail
        out[65536 + ((l * 32 + b) * 256 + o) * 2 + (t - 510)] = cx;        // nc tail
      }
      if (o == 0 && t < 511) out[114688 + (l * 32 + b) * 511 + t] = a_;    // attn
    }
    __syncthreads();
  }
}

extern "C" void kernel_launch(void* const* d_in, const int* in_sizes, int n_in,
                              void* d_out, int out_size, void* d_ws,
                              size_t ws_size, hipStream_t stream) {
  const float* input  = (const float*)d_in[0];
  const float* hidden = (const float*)d_in[1];
  const float* context= (const float*)d_in[2];
  const float* emb_w  = (const float*)d_in[3];
  const float* emb_b  = (const float*)d_in[4];
  const float* conv_w = (const float*)d_in[5];
  const float* conv_b = (const float*)d_in[6];
  const float* rec_w  = (const float*)d_in[7];
  const float* rec_b  = (const float*)d_in[8];
  const float* attn_w = (const float*)d_in[9];
  float* out = (float*)d_out;

  char* ws = (char*)d_ws;
  unsigned short* xf16 = (unsigned short*)ws;                    // 4 x 4,194,304 f16 = 32 MB
  _Float16* igf = (_Float16*)(ws + 33554432);                    // 16,777,216 f16 = 32 MB
  unsigned* rwp = (unsigned*)(ws + 67108864);                    // 1.5 MB
  unsigned* cwp = (unsigned*)(ws + 68681728);                    // 6 MB

  hipLaunchKernelGGL(prep_rw, dim3(1536), dim3(256), 0, stream, rec_w, rwp);
  hipLaunchKernelGGL(prep_cw, dim3(6144), dim3(256), 0, stream, conv_w, cwp);
  hipLaunchKernelGGL(emb_kernel, dim3(8, 4, 32), dim3(256), 0, stream,
                     input, emb_w, emb_b, xf16, out);
  int off = 0;
  for (int l = 0; l < 3; l++) {
    hipLaunchKernelGGL(conv_kernel, dim3(8, 16, 32), dim3(256), 0, stream,
                       xf16, cwp, conv_b, hidden, (unsigned short*)igf, l, off);
    hipLaunchKernelGGL(rec_kernel, dim3(32), dim3(1024), 0, stream,
                       igf, rwp + l * 131072, rec_b + l * 1024,
                       attn_w + l * 256, hidden, context, l,
                       xf16 + (l + 1) * 4194304, out);
    off += l + 1;
  }
}

// Round 3
// 5912.502 us; speedup vs baseline: 1.0148x; 1.0148x over previous
//
#include <hip/hip_runtime.h>

// ---------------------------------------------------------------------------
// Encoder_conv: emb (1x1 conv) -> 3x { multi-tap K=2 convs summed -> LSTM scan
// with per-step attention gating }.
// B=32, W=512, H=256, 4H=1024, NINP=128, K=2, NLAYERS=3.
//
// Round 3: rec_kernel restructure — the bottleneck was LDS hx broadcast
// (512 KB/CU/step through the ~128 B/cyc LDS return path), not just spill.
//  - 512 threads (8 waves), waves_per_eu(2,2) -> 256 VGPR budget enforced.
//  - K-split S=4: thread (s, r) does 8 rows x 1/4 of hx (128 B/thread/step,
//    8x less LDS broadcast). Partials via XOR-swizzled psum (conflict-free).
//  - weights/row: 24 VGPR + 2 LDS(b64) + 6 L2 (b64+quad, coalesced, kept
//    in-loop via opaque-zero asm to defeat LICM register bloat).
// ---------------------------------------------------------------------------

typedef _Float16 h2 __attribute__((ext_vector_type(2)));

static __device__ __forceinline__ float fdot2(unsigned a, unsigned b, float c) {
#if __has_builtin(__builtin_amdgcn_fdot2)
  return __builtin_amdgcn_fdot2(__builtin_bit_cast(h2, a),
                                __builtin_bit_cast(h2, b), c, false);
#else
  h2 x = __builtin_bit_cast(h2, a), y = __builtin_bit_cast(h2, b);
  return c + (float)x[0] * (float)y[0] + (float)x[1] * (float)y[1];
#endif
}

static __device__ __forceinline__ unsigned short f16b(float v) {
  _Float16 h = (_Float16)v;
  return __builtin_bit_cast(unsigned short, h);
}

static __device__ __forceinline__ float sigm(float x) {
  return 1.0f / (1.0f + __expf(-x));
}
static __device__ __forceinline__ float tanh_(float x) {
  return 1.0f - 2.0f / (1.0f + __expf(2.0f * x));
}

// Packs rec_w per layer (131072 dwords/layer) for the S=4 split rec kernel.
// Thread tid=s*128+r owns rows {g*256+hh*128+r} (rl=g*2+hh), K-dwords
// j in [0,32) at global col c = s*32+j.
//   j<24      -> V  : off = (rl*24+j)*512 + tid
//   j=24,25   -> LDS: off = 98304  + (rl*512+tid)*2 + (j-24)
//   j=26,27   -> B64: off = 106496 + (rl*512+tid)*2 + (j-26)
//   j=28..31  -> QUAD:off = 114688 + (rl*512+tid)*4 + (j-28)
__global__ __launch_bounds__(256) void prep_rw(const float* __restrict__ rw,
                                               unsigned* __restrict__ rwp) {
  int idx = blockIdx.x * 256 + threadIdx.x;
  if (idx >= 3 * 131072) return;
  int l = idx / 131072, pos = idx % 131072;
  int tid, rl, j;
  if (pos < 98304) {
    int d = pos >> 9;
    tid = pos & 511;
    rl = d / 24;
    j = d % 24;
  } else if (pos < 106496) {
    int p2 = pos - 98304;
    j = 24 + (p2 & 1);
    tid = (p2 >> 1) & 511;
    rl = p2 >> 10;
  } else if (pos < 114688) {
    int p2 = pos - 106496;
    j = 26 + (p2 & 1);
    tid = (p2 >> 1) & 511;
    rl = p2 >> 10;
  } else {
    int p2 = pos - 114688;
    j = 28 + (p2 & 3);
    tid = (p2 >> 2) & 511;
    rl = p2 >> 11;
  }
  int s = tid >> 7, r = tid & 127, g = rl >> 1, hh = rl & 1;
  int row = g * 256 + hh * 128 + r;
  int c = s * 32 + j;
  const float* src = rw + (l * 1024 + row) * 256 + 2 * c;
  rwp[idx] = (unsigned)f16b(src[0]) | ((unsigned)f16b(src[1]) << 16);
}

// cwp[jj][o][k][d] = pack(f16(conv_w[jj][o][2d][k]), f16(conv_w[jj][o][2d+1][k]))
__global__ __launch_bounds__(256) void prep_cw(const float* __restrict__ cw,
                                               unsigned* __restrict__ cwp) {
  int idx = blockIdx.x * 256 + threadIdx.x;
  if (idx >= 6 * 1024 * 2 * 128) return;
  int d = idx & 127, k = (idx >> 7) & 1, o = (idx >> 8) & 1023, jj = idx >> 18;
  const float* src = cw + ((jj * 1024 + o) * 256 + 2 * d) * 2 + k;
  unsigned v = (unsigned)f16b(src[0]) | ((unsigned)f16b(src[2]) << 16);
  cwp[idx] = v;
}

// x0[b,w,h] = sum_c emb_w[h,c]*input[b,c,w] + emb_b[h]; store f16 + out tail.
__global__ __launch_bounds__(256) void emb_kernel(
    const float* __restrict__ inp, const float* __restrict__ ew,
    const float* __restrict__ eb, unsigned short* __restrict__ x0f,
    float* __restrict__ out) {
  __shared__ float xt[32][65];
  __shared__ float wt[64][33];
  int b = blockIdx.z, w0 = blockIdx.x * 64, h0 = blockIdx.y * 64;
  int tid = threadIdx.x, tx = tid & 15, ty = tid >> 4;
  float acc[4][4] = {};
  for (int c0 = 0; c0 < 128; c0 += 32) {
    __syncthreads();
#pragma unroll
    for (int i = 0; i < 8; i++) {
      int f = i * 256 + tid, c = f >> 6, wl = f & 63;
      xt[c][wl] = inp[(b * 128 + c0 + c) * 512 + w0 + wl];
    }
#pragma unroll
    for (int i = 0; i < 8; i++) {
      int f = i * 256 + tid, h = f >> 5, c = f & 31;
      wt[h][c] = ew[(h0 + h) * 128 + c0 + c];
    }
    __syncthreads();
#pragma unroll
    for (int c = 0; c < 32; c++) {
      float xv[4], wv[4];
#pragma unroll
      for (int q = 0; q < 4; q++) xv[q] = xt[c][ty * 4 + q];
#pragma unroll
      for (int p = 0; p < 4; p++) wv[p] = wt[tx * 4 + p][c];
#pragma unroll
      for (int q = 0; q < 4; q++)
#pragma unroll
        for (int p = 0; p < 4; p++) acc[q][p] += xv[q] * wv[p];
    }
  }
#pragma unroll
  for (int q = 0; q < 4; q++) {
    int w = w0 + ty * 4 + q;
#pragma unroll
    for (int p = 0; p < 4; p++) {
      int h = h0 + tx * 4 + p;
      float v = acc[q][p] + eb[h];
      x0f[(b * 512 + w) * 256 + h] = f16b(v);
      if (w >= 510) out[(b * 256 + h) * 2 + (w - 510)] = v;  // x[0] tail
    }
  }
}

// ig[b,w,o] = sum_j sum_{i,k} xpad_j[b,w-1+k,i] * cw[off+j][o,i,k] + biases
__global__ __launch_bounds__(256) void conv_kernel(
    const unsigned short* __restrict__ xf, const unsigned* __restrict__ cwp,
    const float* __restrict__ cb, const float* __restrict__ hidden,
    unsigned short* __restrict__ igf, int l, int off) {
  __shared__ __align__(16) unsigned xs[65][20];    // [pad-col][dw16], stride 20
  __shared__ __align__(16) unsigned wsm[2][16][66];// [k][dw16][o], pad 66
  int b = blockIdx.z, w0 = blockIdx.x * 64, o0 = blockIdx.y * 64;
  int tid = threadIdx.x, tx = tid & 15, ty = tid >> 4;
  float acc[4][4] = {};
  int nl = l + 1;
  for (int j = 0; j < nl; j++) {
    const unsigned* xj = (const unsigned*)(xf + j * 4194304 + b * 512 * 256);
    const unsigned* cwj = cwp + (off + j) * 262144;
    for (int c0 = 0; c0 < 256; c0 += 32) {
      int d0 = c0 >> 1;
      __syncthreads();
#pragma unroll
      for (int i = 0; i < 5; i++) {
        int f = i * 256 + tid;
        if (f < 1040) {
          int col = f >> 4, dw = f & 15;
          int w = w0 - 1 + col;
          unsigned v;
          if (w >= 0) {
            v = xj[w * 128 + d0 + dw];
          } else {  // left pad: hidden[j][b][i][1]
            const float* hp = hidden + ((j * 32 + b) * 256 + 2 * (d0 + dw)) * 2 + 1;
            v = (unsigned)f16b(hp[0]) | ((unsigned)f16b(hp[2]) << 16);
          }
          xs[col][dw] = v;
        }
      }
#pragma unroll
      for (int i = 0; i < 8; i++) {
        int f = i * 256 + tid;
        int oo = f >> 5, k = (f >> 4) & 1, dw = f & 15;
        wsm[k][dw][oo] = cwj[(o0 + oo) * 256 + k * 128 + d0 + dw];
      }
      __syncthreads();
#pragma unroll
      for (int g = 0; g < 4; g++) {
        uint4 xv[5];
#pragma unroll
        for (int q = 0; q < 5; q++)
          xv[q] = *(const uint4*)&xs[ty * 4 + q][g * 4];
#pragma unroll
        for (int p = 0; p < 4; p++) {
          unsigned wv0[4], wv1[4];
#pragma unroll
          for (int r = 0; r < 4; r++) {
            wv0[r] = wsm[0][g * 4 + r][tx * 4 + p];
            wv1[r] = wsm[1][g * 4 + r][tx * 4 + p];
          }
#pragma unroll
          for (int q = 0; q < 4; q++) {
            float a = acc[q][p];
            a = fdot2(wv0[0], xv[q].x, a);
            a = fdot2(wv0[1], xv[q].y, a);
            a = fdot2(wv0[2], xv[q].z, a);
            a = fdot2(wv0[3], xv[q].w, a);
            a = fdot2(wv1[0], xv[q + 1].x, a);
            a = fdot2(wv1[1], xv[q + 1].y, a);
            a = fdot2(wv1[2], xv[q + 1].z, a);
            a = fdot2(wv1[3], xv[q + 1].w, a);
            acc[q][p] = a;
          }
        }
      }
    }
  }
#pragma unroll
  for (int p = 0; p < 4; p++) {
    int o = o0 + tx * 4 + p;
    float bias = 0.f;
    for (int j = 0; j < nl; j++) bias += cb[(off + j) * 1024 + o];
#pragma unroll
    for (int q = 0; q < 4; q++) {
      int w = w0 + ty * 4 + q;
      igf[(b * 512 + w) * 1024 + o] = f16b(acc[q][p] + bias);
    }
  }
}

// One WG per batch; 512 threads; thread (s=tid>>7, r=tid&127) computes
// 8 partial row-dots over 1/4 of hx. 512 sequential steps.
__global__ __launch_bounds__(512)
__attribute__((amdgpu_waves_per_eu(2, 2)))
void rec_kernel(const _Float16* __restrict__ igf, const unsigned* __restrict__ rwp_l,
                const float* __restrict__ rb, const float* __restrict__ aw,
                const float* __restrict__ hidden, const float* __restrict__ context,
                int l, unsigned short* __restrict__ xnext, float* __restrict__ out) {
  __shared__ __align__(16) unsigned long long w_lds[8 * 512];  // 32 KB
  __shared__ __align__(16) float psum[4 * 256 * 4];            // [g][u][4] 16 KB
  __shared__ __align__(16) unsigned short hx_half[256];
  __shared__ float red[4];
  int b = blockIdx.x, tid = threadIdx.x;
  int s = tid >> 7, r = tid & 127;

  unsigned wv[192];
#pragma unroll
  for (int d = 0; d < 192; d++) wv[d] = rwp_l[d * 512 + tid];
  {
    const unsigned long long* gL = (const unsigned long long*)(rwp_l + 98304);
#pragma unroll
    for (int rl = 0; rl < 8; rl++) w_lds[rl * 512 + tid] = gL[rl * 512 + tid];
  }
  const unsigned long long* gB = (const unsigned long long*)(rwp_l + 106496);
  const uint4* gA = (const uint4*)(rwp_l + 114688);

  float cx = 0.f, awj = 0.f, rb0 = 0, rb1 = 0, rb2 = 0, rb3 = 0;
  if (tid < 256) {
    awj = aw[tid];
    rb0 = rb[tid];
    rb1 = rb[256 + tid];
    rb2 = rb[512 + tid];
    rb3 = rb[768 + tid];
    hx_half[tid] = f16b(hidden[(((l + 1) * 32 + b) * 256 + tid) * 2 + 1]);
    cx = context[((l * 32 + b) * 256 + tid) * 2 + 1];
  }
  __syncthreads();

  const _Float16* igp = igf + (b * 512) * 1024 + tid;
  const uint4* hq = ((const uint4*)hx_half) + 8 * s;

  for (int t = 0; t < 512; t++) {
    int woff = 0;
    asm volatile("" : "+v"(woff));  // opaque zero: keep gA/gB loads in-loop
    float ig0 = 0, ig1 = 0, ig2 = 0, ig3 = 0;
    if (tid < 256) {
      const _Float16* ip = igp + t * 1024;
      ig0 = (float)ip[0];
      ig1 = (float)ip[256];
      ig2 = (float)ip[512];
      ig3 = (float)ip[768];
    }
    float acc[8] = {};
#pragma unroll
    for (int q = 0; q < 6; q++) {
      uint4 h = hq[q];
#pragma unroll
      for (int rl = 0; rl < 8; rl++) {
        acc[rl] = fdot2(wv[rl * 24 + 4 * q + 0], h.x, acc[rl]);
        acc[rl] = fdot2(wv[rl * 24 + 4 * q + 1], h.y, acc[rl]);
        acc[rl] = fdot2(wv[rl * 24 + 4 * q + 2], h.z, acc[rl]);
        acc[rl] = fdot2(wv[rl * 24 + 4 * q + 3], h.w, acc[rl]);
      }
    }
    {
      uint4 h = hq[6];
#pragma unroll
      for (int rl = 0; rl < 8; rl++) {
        unsigned long long wl = w_lds[rl * 512 + tid];
        unsigned long long wb = gB[rl * 512 + tid + woff];
        acc[rl] = fdot2((unsigned)wl, h.x, acc[rl]);
        acc[rl] = fdot2((unsigned)(wl >> 32), h.y, acc[rl]);
        acc[rl] = fdot2((unsigned)wb, h.z, acc[rl]);
        acc[rl] = fdot2((unsigned)(wb >> 32), h.w, acc[rl]);
      }
    }
    {
      uint4 h = hq[7];
#pragma unroll
      for (int rl = 0; rl < 8; rl++) {
        uint4 wa = gA[rl * 512 + tid + woff];
        acc[rl] = fdot2(wa.x, h.x, acc[rl]);
        acc[rl] = fdot2(wa.y, h.y, acc[rl]);
        acc[rl] = fdot2(wa.z, h.z, acc[rl]);
        acc[rl] = fdot2(wa.w, h.w, acc[rl]);
      }
    }
    // scatter partials: row rl -> psum[g][u][s ^ (u&3)] (XOR swizzle:
    // write conflict-free b32, read b128; sum order irrelevant)
#pragma unroll
    for (int rl = 0; rl < 8; rl++) {
      int g = rl >> 1, u = (rl & 1) * 128 + r;
      psum[(g * 256 + u) * 4 + (s ^ (u & 3))] = acc[rl];
    }
    __syncthreads();

    float h_val = 0.f;
    if (tid < 256) {
      const float4* pp = (const float4*)psum + tid;  // [g][u][.]
      float4 p0 = pp[0], p1 = pp[256], p2 = pp[512], p3 = pp[768];
      float g_i = ig0 + rb0 + p0.x + p0.y + p0.z + p0.w;
      float g_f = ig1 + rb1 + p1.x + p1.y + p1.z + p1.w;
      float g_c = ig2 + rb2 + p2.x + p2.y + p2.z + p2.w;
      float g_o = ig3 + rb3 + p3.x + p3.y + p3.z + p3.w;
      cx = sigm(g_f) * cx + sigm(g_i) * tanh_(g_c);
      h_val = sigm(g_o) * tanh_(cx);
      float part = h_val * awj;
#pragma unroll
      for (int sh = 32; sh > 0; sh >>= 1) part += __shfl_xor(part, sh);
      if ((tid & 63) == 0) red[tid >> 6] = part;
    }
    __syncthreads();
    if (tid < 256) {
      float a_ = sigm(red[0] + red[1] + red[2] + red[3]);
      float hg = (t < 511) ? h_val * a_ : h_val;
      hx_half[tid] = f16b(hg);
      xnext[(b * 512 + t) * 256 + tid] = f16b(hg);
      if (t >= 510) {
        out[(((l + 1) * 32 + b) * 256 + tid) * 2 + (t - 510)] = hg;        // x tail
        out[65536 + ((l * 32 + b) * 256 + tid) * 2 + (t - 510)] = cx;      // nc tail
      }
      if (tid == 0 && t < 511) out[114688 + (l * 32 + b) * 511 + t] = a_;  // attn
    }
    __syncthreads();
  }
}

extern "C" void kernel_launch(void* const* d_in, const int* in_sizes, int n_in,
                              void* d_out, int out_size, void* d_ws,
                              size_t ws_size, hipStream_t stream) {
  const float* input  = (const float*)d_in[0];
  const float* hidden = (const float*)d_in[1];
  const float* context= (const float*)d_in[2];
  const float* emb_w  = (const float*)d_in[3];
  const float* emb_b  = (const float*)d_in[4];
  const float* conv_w = (const float*)d_in[5];
  const float* conv_b = (const float*)d_in[6];
  const float* rec_w  = (const float*)d_in[7];
  const float* rec_b  = (const float*)d_in[8];
  const float* attn_w = (const float*)d_in[9];
  float* out = (float*)d_out;

  char* ws = (char*)d_ws;
  unsigned short* xf16 = (unsigned short*)ws;                    // 4 x 4,194,304 f16 = 32 MB
  _Float16* igf = (_Float16*)(ws + 33554432);                    // 16,777,216 f16 = 32 MB
  unsigned* rwp = (unsigned*)(ws + 67108864);                    // 1.5 MB
  unsigned* cwp = (unsigned*)(ws + 68681728);                    // 6 MB

  hipLaunchKernelGGL(prep_rw, dim3(1536), dim3(256), 0, stream, rec_w, rwp);
  hipLaunchKernelGGL(prep_cw, dim3(6144), dim3(256), 0, stream, conv_w, cwp);
  hipLaunchKernelGGL(emb_kernel, dim3(8, 4, 32), dim3(256), 0, stream,
                     input, emb_w, emb_b, xf16, out);
  int off = 0;
  for (int l = 0; l < 3; l++) {
    hipLaunchKernelGGL(conv_kernel, dim3(8, 16, 32), dim3(256), 0, stream,
                       xf16, cwp, conv_b, hidden, (unsigned short*)igf, l, off);
    hipLaunchKernelGGL(rec_kernel, dim3(32), dim3(512), 0, stream,
                       igf, rwp + l * 131072, rec_b + l * 1024,
                       attn_w + l * 256, hidden, context, l,
                       xf16 + (l + 1) * 4194304, out);
    off += l + 1;
  }
}

// Round 4
// 5281.263 us; speedup vs baseline: 1.1361x; 1.1195x over previous
//
#include <hip/hip_runtime.h>

// ---------------------------------------------------------------------------
// Encoder_conv: emb (1x1 conv) -> 3x { multi-tap K=2 convs summed -> LSTM scan
// with per-step attention gating }.
// B=32, W=512, H=256, 4H=1024, NINP=128, K=2, NLAYERS=3.
//
// Round 4: rec_kernel — force weight residency. Rounds 1-3 were all
// L1-bound on weight re-reads (~3.1 us/step = bytes/64Bcyc): the allocator
// kept sinking "register" weight loads back into the loop. Now:
//   96 dw/thread -> AGPRs (explicit v_accvgpr_write/read asm, un-sinkable)
//   96 dw/thread -> VGPR array (+opaque pins; pressure 231 <= 256 budget)
//   64 dw/thread -> LDS uint4[16][512] (conflict-free ds_read_b128, 128 KB)
// psum relayout [s][1024] (conflict-free both phases); global stores moved
// after the 3rd barrier so the drain overlaps next step's phase 1.
// ---------------------------------------------------------------------------

typedef _Float16 h2 __attribute__((ext_vector_type(2)));

static __device__ __forceinline__ float fdot2(unsigned a, unsigned b, float c) {
#if __has_builtin(__builtin_amdgcn_fdot2)
  return __builtin_amdgcn_fdot2(__builtin_bit_cast(h2, a),
                                __builtin_bit_cast(h2, b), c, false);
#else
  h2 x = __builtin_bit_cast(h2, a), y = __builtin_bit_cast(h2, b);
  return c + (float)x[0] * (float)y[0] + (float)x[1] * (float)y[1];
#endif
}

static __device__ __forceinline__ unsigned short f16b(float v) {
  _Float16 h = (_Float16)v;
  return __builtin_bit_cast(unsigned short, h);
}

static __device__ __forceinline__ float sigm(float x) {
  return 1.0f / (1.0f + __expf(-x));
}
static __device__ __forceinline__ float tanh_(float x) {
  return 1.0f - 2.0f / (1.0f + __expf(2.0f * x));
}

// Packs rec_w per layer (131072 dwords/layer) for the S=4 split rec kernel.
// Thread tid=s*128+r owns rows row=g*256+hh*128+r (rl=g*2+hh, rl=0..7),
// hx-pair columns cp = s*32 + cpo, cpo in [0,32):
//   cpo  0..11 -> VGPR : off = (rl*12+cpo)*512 + tid
//   cpo 12..23 -> AGPR : off = 49152 + (rl*12+cpo-12)*512 + tid
//   cpo 24..31 -> LDS  : chunk c=rl*2+((cpo-24)>>2), k=(cpo-24)&3
//                        off = 98304 + c*2048 + tid*4 + k
__global__ __launch_bounds__(256) void prep_rw(const float* __restrict__ rw,
                                               unsigned* __restrict__ rwp) {
  int idx = blockIdx.x * 256 + threadIdx.x;
  if (idx >= 3 * 131072) return;
  int l = idx / 131072, pos = idx % 131072;
  int tid, rl, cpo;
  if (pos < 49152) {
    int d = pos >> 9;
    tid = pos & 511;
    rl = d / 12;
    cpo = d % 12;
  } else if (pos < 98304) {
    int p = pos - 49152;
    int d = p >> 9;
    tid = p & 511;
    rl = d / 12;
    cpo = 12 + d % 12;
  } else {
    int p = pos - 98304;
    int c = p >> 11, rem = p & 2047;
    tid = rem >> 2;
    int k = rem & 3;
    rl = c >> 1;
    cpo = 24 + (c & 1) * 4 + k;
  }
  int s = tid >> 7, r = tid & 127, g = rl >> 1, hh = rl & 1;
  int row = g * 256 + hh * 128 + r;
  int cp = s * 32 + cpo;
  const float* src = rw + (l * 1024 + row) * 256 + 2 * cp;
  rwp[idx] = (unsigned)f16b(src[0]) | ((unsigned)f16b(src[1]) << 16);
}

// cwp[jj][o][k][d] = pack(f16(conv_w[jj][o][2d][k]), f16(conv_w[jj][o][2d+1][k]))
__global__ __launch_bounds__(256) void prep_cw(const float* __restrict__ cw,
                                               unsigned* __restrict__ cwp) {
  int idx = blockIdx.x * 256 + threadIdx.x;
  if (idx >= 6 * 1024 * 2 * 128) return;
  int d = idx & 127, k = (idx >> 7) & 1, o = (idx >> 8) & 1023, jj = idx >> 18;
  const float* src = cw + ((jj * 1024 + o) * 256 + 2 * d) * 2 + k;
  unsigned v = (unsigned)f16b(src[0]) | ((unsigned)f16b(src[2]) << 16);
  cwp[idx] = v;
}

// x0[b,w,h] = sum_c emb_w[h,c]*input[b,c,w] + emb_b[h]; store f16 + out tail.
__global__ __launch_bounds__(256) void emb_kernel(
    const float* __restrict__ inp, const float* __restrict__ ew,
    const float* __restrict__ eb, unsigned short* __restrict__ x0f,
    float* __restrict__ out) {
  __shared__ float xt[32][65];
  __shared__ float wt[64][33];
  int b = blockIdx.z, w0 = blockIdx.x * 64, h0 = blockIdx.y * 64;
  int tid = threadIdx.x, tx = tid & 15, ty = tid >> 4;
  float acc[4][4] = {};
  for (int c0 = 0; c0 < 128; c0 += 32) {
    __syncthreads();
#pragma unroll
    for (int i = 0; i < 8; i++) {
      int f = i * 256 + tid, c = f >> 6, wl = f & 63;
      xt[c][wl] = inp[(b * 128 + c0 + c) * 512 + w0 + wl];
    }
#pragma unroll
    for (int i = 0; i < 8; i++) {
      int f = i * 256 + tid, h = f >> 5, c = f & 31;
      wt[h][c] = ew[(h0 + h) * 128 + c0 + c];
    }
    __syncthreads();
#pragma unroll
    for (int c = 0; c < 32; c++) {
      float xv[4], wv[4];
#pragma unroll
      for (int q = 0; q < 4; q++) xv[q] = xt[c][ty * 4 + q];
#pragma unroll
      for (int p = 0; p < 4; p++) wv[p] = wt[tx * 4 + p][c];
#pragma unroll
      for (int q = 0; q < 4; q++)
#pragma unroll
        for (int p = 0; p < 4; p++) acc[q][p] += xv[q] * wv[p];
    }
  }
#pragma unroll
  for (int q = 0; q < 4; q++) {
    int w = w0 + ty * 4 + q;
#pragma unroll
    for (int p = 0; p < 4; p++) {
      int h = h0 + tx * 4 + p;
      float v = acc[q][p] + eb[h];
      x0f[(b * 512 + w) * 256 + h] = f16b(v);
      if (w >= 510) out[(b * 256 + h) * 2 + (w - 510)] = v;  // x[0] tail
    }
  }
}

// ig[b,w,o] = sum_j sum_{i,k} xpad_j[b,w-1+k,i] * cw[off+j][o,i,k] + biases
__global__ __launch_bounds__(256) void conv_kernel(
    const unsigned short* __restrict__ xf, const unsigned* __restrict__ cwp,
    const float* __restrict__ cb, const float* __restrict__ hidden,
    unsigned short* __restrict__ igf, int l, int off) {
  __shared__ __align__(16) unsigned xs[65][20];    // [pad-col][dw16], stride 20
  __shared__ __align__(16) unsigned wsm[2][16][66];// [k][dw16][o], pad 66
  int b = blockIdx.z, w0 = blockIdx.x * 64, o0 = blockIdx.y * 64;
  int tid = threadIdx.x, tx = tid & 15, ty = tid >> 4;
  float acc[4][4] = {};
  int nl = l + 1;
  for (int j = 0; j < nl; j++) {
    const unsigned* xj = (const unsigned*)(xf + j * 4194304 + b * 512 * 256);
    const unsigned* cwj = cwp + (off + j) * 262144;
    for (int c0 = 0; c0 < 256; c0 += 32) {
      int d0 = c0 >> 1;
      __syncthreads();
#pragma unroll
      for (int i = 0; i < 5; i++) {
        int f = i * 256 + tid;
        if (f < 1040) {
          int col = f >> 4, dw = f & 15;
          int w = w0 - 1 + col;
          unsigned v;
          if (w >= 0) {
            v = xj[w * 128 + d0 + dw];
          } else {  // left pad: hidden[j][b][i][1]
            const float* hp = hidden + ((j * 32 + b) * 256 + 2 * (d0 + dw)) * 2 + 1;
            v = (unsigned)f16b(hp[0]) | ((unsigned)f16b(hp[2]) << 16);
          }
          xs[col][dw] = v;
        }
      }
#pragma unroll
      for (int i = 0; i < 8; i++) {
        int f = i * 256 + tid;
        int oo = f >> 5, k = (f >> 4) & 1, dw = f & 15;
        wsm[k][dw][oo] = cwj[(o0 + oo) * 256 + k * 128 + d0 + dw];
      }
      __syncthreads();
#pragma unroll
      for (int g = 0; g < 4; g++) {
        uint4 xv[5];
#pragma unroll
        for (int q = 0; q < 5; q++)
          xv[q] = *(const uint4*)&xs[ty * 4 + q][g * 4];
#pragma unroll
        for (int p = 0; p < 4; p++) {
          unsigned wv0[4], wv1[4];
#pragma unroll
          for (int r = 0; r < 4; r++) {
            wv0[r] = wsm[0][g * 4 + r][tx * 4 + p];
            wv1[r] = wsm[1][g * 4 + r][tx * 4 + p];
          }
#pragma unroll
          for (int q = 0; q < 4; q++) {
            float a = acc[q][p];
            a = fdot2(wv0[0], xv[q].x, a);
            a = fdot2(wv0[1], xv[q].y, a);
            a = fdot2(wv0[2], xv[q].z, a);
            a = fdot2(wv0[3], xv[q].w, a);
            a = fdot2(wv1[0], xv[q + 1].x, a);
            a = fdot2(wv1[1], xv[q + 1].y, a);
            a = fdot2(wv1[2], xv[q + 1].z, a);
            a = fdot2(wv1[3], xv[q + 1].w, a);
            acc[q][p] = a;
          }
        }
      }
    }
  }
#pragma unroll
  for (int p = 0; p < 4; p++) {
    int o = o0 + tx * 4 + p;
    float bias = 0.f;
    for (int j = 0; j < nl; j++) bias += cb[(off + j) * 1024 + o];
#pragma unroll
    for (int q = 0; q < 4; q++) {
      int w = w0 + ty * 4 + q;
      igf[(b * 512 + w) * 1024 + o] = f16b(acc[q][p] + bias);
    }
  }
}

// One WG per batch; 512 threads; thread (s=tid>>7, r=tid&127) computes
// 8 partial row-dots over 1/4 of hx. 512 sequential steps.
__global__ __launch_bounds__(512)
__attribute__((amdgpu_waves_per_eu(2, 2)))
void rec_kernel(const _Float16* __restrict__ igf, const unsigned* __restrict__ rwp_l,
                const float* __restrict__ rb, const float* __restrict__ aw,
                const float* __restrict__ hidden, const float* __restrict__ context,
                int l, unsigned short* __restrict__ xnext, float* __restrict__ out) {
  __shared__ __align__(16) uint4 w_lds4[16 * 512];          // 128 KB
  __shared__ __align__(16) float psum[4 * 1024];            // [s][g*256+u] 16 KB
  __shared__ __align__(16) unsigned short hx_half[256];
  __shared__ float red[4];
  int b = blockIdx.x, tid = threadIdx.x;
  int s = tid >> 7, r = tid & 127;

  // 96 dwords -> VGPR array (pinned opaque so loads can't be sunk in-loop)
  unsigned wv[96];
#pragma unroll
  for (int d = 0; d < 96; d++) wv[d] = rwp_l[d * 512 + tid];
#pragma unroll
  for (int d = 0; d < 96; d++) asm volatile("" : "+v"(wv[d]));

  // 96 dwords -> AGPRs (explicit accvgpr write; un-rematerializable)
  unsigned wa[96];
#pragma unroll
  for (int d = 0; d < 96; d++) {
    unsigned v = rwp_l[49152 + d * 512 + tid];
    asm volatile("v_accvgpr_write_b32 %0, %1" : "=a"(wa[d]) : "v"(v));
  }

  // 64 dwords -> LDS, [chunk][tid] uint4 (conflict-free ds_read_b128)
  {
    const uint4* g16 = (const uint4*)(rwp_l + 98304);
#pragma unroll
    for (int c = 0; c < 16; c++) w_lds4[c * 512 + tid] = g16[c * 512 + tid];
  }

  float cx = 0.f, awj = 0.f, rb0 = 0, rb1 = 0, rb2 = 0, rb3 = 0;
  if (tid < 256) {
    awj = aw[tid];
    rb0 = rb[tid];
    rb1 = rb[256 + tid];
    rb2 = rb[512 + tid];
    rb3 = rb[768 + tid];
    hx_half[tid] = f16b(hidden[(((l + 1) * 32 + b) * 256 + tid) * 2 + 1]);
    cx = context[((l * 32 + b) * 256 + tid) * 2 + 1];
  }
  __syncthreads();

  const _Float16* igp = igf + (b * 512) * 1024 + tid;
  const uint4* hq = ((const uint4*)hx_half) + 8 * s;

  for (int t = 0; t < 512; t++) {
    float ig0 = 0, ig1 = 0, ig2 = 0, ig3 = 0;
    if (tid < 256) {
      const _Float16* ip = igp + t * 1024;
      ig0 = (float)ip[0];
      ig1 = (float)ip[256];
      ig2 = (float)ip[512];
      ig3 = (float)ip[768];
    }
    float acc[8] = {};
    // quads 0..2: VGPR weights (per-wave hq[q] is lane-uniform -> broadcast)
#pragma unroll
    for (int q = 0; q < 3; q++) {
      uint4 h = hq[q];
#pragma unroll
      for (int rl = 0; rl < 8; rl++) {
        acc[rl] = fdot2(wv[rl * 12 + q * 4 + 0], h.x, acc[rl]);
        acc[rl] = fdot2(wv[rl * 12 + q * 4 + 1], h.y, acc[rl]);
        acc[rl] = fdot2(wv[rl * 12 + q * 4 + 2], h.z, acc[rl]);
        acc[rl] = fdot2(wv[rl * 12 + q * 4 + 3], h.w, acc[rl]);
      }
    }
    // quads 3..5: AGPR weights
#pragma unroll
    for (int q = 3; q < 6; q++) {
      uint4 h = hq[q];
#pragma unroll
      for (int rl = 0; rl < 8; rl++) {
        unsigned w0_, w1_, w2_, w3_;
        asm volatile("v_accvgpr_read_b32 %0, %1" : "=v"(w0_) : "a"(wa[rl * 12 + (q - 3) * 4 + 0]));
        asm volatile("v_accvgpr_read_b32 %0, %1" : "=v"(w1_) : "a"(wa[rl * 12 + (q - 3) * 4 + 1]));
        asm volatile("v_accvgpr_read_b32 %0, %1" : "=v"(w2_) : "a"(wa[rl * 12 + (q - 3) * 4 + 2]));
        asm volatile("v_accvgpr_read_b32 %0, %1" : "=v"(w3_) : "a"(wa[rl * 12 + (q - 3) * 4 + 3]));
        acc[rl] = fdot2(w0_, h.x, acc[rl]);
        acc[rl] = fdot2(w1_, h.y, acc[rl]);
        acc[rl] = fdot2(w2_, h.z, acc[rl]);
        acc[rl] = fdot2(w3_, h.w, acc[rl]);
      }
    }
    // quads 6..7: LDS weights
#pragma unroll
    for (int q = 6; q < 8; q++) {
      uint4 h = hq[q];
#pragma unroll
      for (int rl = 0; rl < 8; rl++) {
        uint4 lw = w_lds4[(rl * 2 + (q - 6)) * 512 + tid];
        acc[rl] = fdot2(lw.x, h.x, acc[rl]);
        acc[rl] = fdot2(lw.y, h.y, acc[rl]);
        acc[rl] = fdot2(lw.z, h.z, acc[rl]);
        acc[rl] = fdot2(lw.w, h.w, acc[rl]);
      }
    }
    // partials: psum[s][row] — write lanes r-consecutive, conflict-free
#pragma unroll
    for (int rl = 0; rl < 8; rl++) {
      int g = rl >> 1, hh = rl & 1;
      psum[s * 1024 + g * 256 + hh * 128 + r] = acc[rl];
    }
    __syncthreads();

    float h_val = 0.f, hg = 0.f, a_ = 0.f;
    if (tid < 256) {
      float g_i = ig0 + rb0, g_f = ig1 + rb1, g_c = ig2 + rb2, g_o = ig3 + rb3;
#pragma unroll
      for (int s2 = 0; s2 < 4; s2++) {
        g_i += psum[s2 * 1024 + tid];
        g_f += psum[s2 * 1024 + 256 + tid];
        g_c += psum[s2 * 1024 + 512 + tid];
        g_o += psum[s2 * 1024 + 768 + tid];
      }
      cx = sigm(g_f) * cx + sigm(g_i) * tanh_(g_c);
      h_val = sigm(g_o) * tanh_(cx);
      float part = h_val * awj;
#pragma unroll
      for (int sh = 32; sh > 0; sh >>= 1) part += __shfl_xor(part, sh);
      if ((tid & 63) == 0) red[tid >> 6] = part;
    }
    __syncthreads();
    if (tid < 256) {
      a_ = sigm(red[0] + red[1] + red[2] + red[3]);
      hg = (t < 511) ? h_val * a_ : h_val;
      hx_half[tid] = f16b(hg);
    }
    __syncthreads();
    // Global stores AFTER the barrier: the vmcnt drain lands at next step's
    // psum barrier, hidden under ~1500 cyc of phase-1 compute.
    if (tid < 256) {
      xnext[(b * 512 + t) * 256 + tid] = f16b(hg);
      if (t >= 510) {
        out[(((l + 1) * 32 + b) * 256 + tid) * 2 + (t - 510)] = hg;        // x tail
        out[65536 + ((l * 32 + b) * 256 + tid) * 2 + (t - 510)] = cx;      // nc tail
      }
      if (tid == 0 && t < 511) out[114688 + (l * 32 + b) * 511 + t] = a_;  // attn
    }
  }
}

extern "C" void kernel_launch(void* const* d_in, const int* in_sizes, int n_in,
                              void* d_out, int out_size, void* d_ws,
                              size_t ws_size, hipStream_t stream) {
  const float* input  = (const float*)d_in[0];
  const float* hidden = (const float*)d_in[1];
  const float* context= (const float*)d_in[2];
  const float* emb_w  = (const float*)d_in[3];
  const float* emb_b  = (const float*)d_in[4];
  const float* conv_w = (const float*)d_in[5];
  const float* conv_b = (const float*)d_in[6];
  const float* rec_w  = (const float*)d_in[7];
  const float* rec_b  = (const float*)d_in[8];
  const float* attn_w = (const float*)d_in[9];
  float* out = (float*)d_out;

  char* ws = (char*)d_ws;
  unsigned short* xf16 = (unsigned short*)ws;                    // 4 x 4,194,304 f16 = 32 MB
  _Float16* igf = (_Float16*)(ws + 33554432);                    // 16,777,216 f16 = 32 MB
  unsigned* rwp = (unsigned*)(ws + 67108864);                    // 1.5 MB
  unsigned* cwp = (unsigned*)(ws + 68681728);                    // 6 MB

  hipLaunchKernelGGL(prep_rw, dim3(1536), dim3(256), 0, stream, rec_w, rwp);
  hipLaunchKernelGGL(prep_cw, dim3(6144), dim3(256), 0, stream, conv_w, cwp);
  hipLaunchKernelGGL(emb_kernel, dim3(8, 4, 32), dim3(256), 0, stream,
                     input, emb_w, emb_b, xf16, out);
  int off = 0;
  for (int l = 0; l < 3; l++) {
    hipLaunchKernelGGL(conv_kernel, dim3(8, 16, 32), dim3(256), 0, stream,
                       xf16, cwp, conv_b, hidden, (unsigned short*)igf, l, off);
    hipLaunchKernelGGL(rec_kernel, dim3(32), dim3(512), 0, stream,
                       igf, rwp + l * 131072, rec_b + l * 1024,
                       attn_w + l * 256, hidden, context, l,
                       xf16 + (l + 1) * 4194304, out);
    off += l + 1;
  }
}

// Round 5
// 4405.247 us; speedup vs baseline: 1.3621x; 1.1989x over previous
//
#include <hip/hip_runtime.h>

// ---------------------------------------------------------------------------
// Encoder_conv: emb (1x1 conv) -> 3x { multi-tap K=2 convs summed -> LSTM scan
// with per-step attention gating }.
// B=32, W=512, H=256, 4H=1024, NINP=128, K=2, NLAYERS=3.
//
// Round 5: rec_kernel restructure — 1 barrier/step.
//  - lane (s=tid&3, u=tid>>2): 8 rows x 64-elem K-chunk; butterfly shfl_xor
//    over s => every lane holds all 4 gates of unit u2=u+128*(s&1). No psum.
//  - deferred attention gating: hx stored RAW; m=a_(t-1) applied as scalar
//    to next step's dot sums (dot(w, a*h) = a*dot(w,h)). Gated xnext stores
//    deferred one step. hx_buf/red double-buffered -> single __syncthreads.
//  - weights: 192 dw/thread pinned VGPRs + 64 dw/thread LDS (128 KB,
//    conflict-free b128). No AGPR reads.
// ---------------------------------------------------------------------------

typedef _Float16 h2 __attribute__((ext_vector_type(2)));

static __device__ __forceinline__ float fdot2(unsigned a, unsigned b, float c) {
#if __has_builtin(__builtin_amdgcn_fdot2)
  return __builtin_amdgcn_fdot2(__builtin_bit_cast(h2, a),
                                __builtin_bit_cast(h2, b), c, false);
#else
  h2 x = __builtin_bit_cast(h2, a), y = __builtin_bit_cast(h2, b);
  return c + (float)x[0] * (float)y[0] + (float)x[1] * (float)y[1];
#endif
}

static __device__ __forceinline__ unsigned short f16b(float v) {
  _Float16 h = (_Float16)v;
  return __builtin_bit_cast(unsigned short, h);
}

static __device__ __forceinline__ float sigm(float x) {
  return 1.0f / (1.0f + __expf(-x));
}
static __device__ __forceinline__ float tanh_(float x) {
  return 1.0f - 2.0f / (1.0f + __expf(2.0f * x));
}

// Packs rec_w per layer (131072 dwords/layer) for the butterfly rec kernel.
// Thread tid: s=tid&3, u=tid>>2; rows row=(rl>>1)*256+(rl&1)*128+u (rl=0..7);
// K-pairs j in [0,32) at global pair cp = s*32+j:
//   j<24      -> VGPR: off = (rl*24+j)*512 + tid
//   j=24..31  -> LDS : c = rl*2+((j-24)>>2), k=(j-24)&3
//                      off = 98304 + c*2048 + tid*4 + k
__global__ __launch_bounds__(256) void prep_rw(const float* __restrict__ rw,
                                               unsigned* __restrict__ rwp) {
  int idx = blockIdx.x * 256 + threadIdx.x;
  if (idx >= 3 * 131072) return;
  int l = idx / 131072, pos = idx % 131072;
  int tid, rl, j;
  if (pos < 98304) {
    int d = pos >> 9;
    tid = pos & 511;
    rl = d / 24;
    j = d % 24;
  } else {
    int p = pos - 98304;
    int c = p >> 11, rem = p & 2047;
    tid = rem >> 2;
    int k = rem & 3;
    rl = c >> 1;
    j = 24 + (c & 1) * 4 + k;
  }
  int s = tid & 3, u = tid >> 2;
  int row = (rl >> 1) * 256 + (rl & 1) * 128 + u;
  int cp = s * 32 + j;
  const float* src = rw + (l * 1024 + row) * 256 + 2 * cp;
  rwp[idx] = (unsigned)f16b(src[0]) | ((unsigned)f16b(src[1]) << 16);
}

// cwp[jj][o][k][d] = pack(f16(conv_w[jj][o][2d][k]), f16(conv_w[jj][o][2d+1][k]))
__global__ __launch_bounds__(256) void prep_cw(const float* __restrict__ cw,
                                               unsigned* __restrict__ cwp) {
  int idx = blockIdx.x * 256 + threadIdx.x;
  if (idx >= 6 * 1024 * 2 * 128) return;
  int d = idx & 127, k = (idx >> 7) & 1, o = (idx >> 8) & 1023, jj = idx >> 18;
  const float* src = cw + ((jj * 1024 + o) * 256 + 2 * d) * 2 + k;
  unsigned v = (unsigned)f16b(src[0]) | ((unsigned)f16b(src[2]) << 16);
  cwp[idx] = v;
}

// x0[b,w,h] = sum_c emb_w[h,c]*input[b,c,w] + emb_b[h]; store f16 + out tail.
__global__ __launch_bounds__(256) void emb_kernel(
    const float* __restrict__ inp, const float* __restrict__ ew,
    const float* __restrict__ eb, unsigned short* __restrict__ x0f,
    float* __restrict__ out) {
  __shared__ float xt[32][65];
  __shared__ float wt[64][33];
  int b = blockIdx.z, w0 = blockIdx.x * 64, h0 = blockIdx.y * 64;
  int tid = threadIdx.x, tx = tid & 15, ty = tid >> 4;
  float acc[4][4] = {};
  for (int c0 = 0; c0 < 128; c0 += 32) {
    __syncthreads();
#pragma unroll
    for (int i = 0; i < 8; i++) {
      int f = i * 256 + tid, c = f >> 6, wl = f & 63;
      xt[c][wl] = inp[(b * 128 + c0 + c) * 512 + w0 + wl];
    }
#pragma unroll
    for (int i = 0; i < 8; i++) {
      int f = i * 256 + tid, h = f >> 5, c = f & 31;
      wt[h][c] = ew[(h0 + h) * 128 + c0 + c];
    }
    __syncthreads();
#pragma unroll
    for (int c = 0; c < 32; c++) {
      float xv[4], wv[4];
#pragma unroll
      for (int q = 0; q < 4; q++) xv[q] = xt[c][ty * 4 + q];
#pragma unroll
      for (int p = 0; p < 4; p++) wv[p] = wt[tx * 4 + p][c];
#pragma unroll
      for (int q = 0; q < 4; q++)
#pragma unroll
        for (int p = 0; p < 4; p++) acc[q][p] += xv[q] * wv[p];
    }
  }
#pragma unroll
  for (int q = 0; q < 4; q++) {
    int w = w0 + ty * 4 + q;
#pragma unroll
    for (int p = 0; p < 4; p++) {
      int h = h0 + tx * 4 + p;
      float v = acc[q][p] + eb[h];
      x0f[(b * 512 + w) * 256 + h] = f16b(v);
      if (w >= 510) out[(b * 256 + h) * 2 + (w - 510)] = v;  // x[0] tail
    }
  }
}

// ig[b,w,o] = sum_j sum_{i,k} xpad_j[b,w-1+k,i] * cw[off+j][o,i,k] + biases
__global__ __launch_bounds__(256) void conv_kernel(
    const unsigned short* __restrict__ xf, const unsigned* __restrict__ cwp,
    const float* __restrict__ cb, const float* __restrict__ hidden,
    unsigned short* __restrict__ igf, int l, int off) {
  __shared__ __align__(16) unsigned xs[65][20];    // [pad-col][dw16], stride 20
  __shared__ __align__(16) unsigned wsm[2][16][66];// [k][dw16][o], pad 66
  int b = blockIdx.z, w0 = blockIdx.x * 64, o0 = blockIdx.y * 64;
  int tid = threadIdx.x, tx = tid & 15, ty = tid >> 4;
  float acc[4][4] = {};
  int nl = l + 1;
  for (int j = 0; j < nl; j++) {
    const unsigned* xj = (const unsigned*)(xf + j * 4194304 + b * 512 * 256);
    const unsigned* cwj = cwp + (off + j) * 262144;
    for (int c0 = 0; c0 < 256; c0 += 32) {
      int d0 = c0 >> 1;
      __syncthreads();
#pragma unroll
      for (int i = 0; i < 5; i++) {
        int f = i * 256 + tid;
        if (f < 1040) {
          int col = f >> 4, dw = f & 15;
          int w = w0 - 1 + col;
          unsigned v;
          if (w >= 0) {
            v = xj[w * 128 + d0 + dw];
          } else {  // left pad: hidden[j][b][i][1]
            const float* hp = hidden + ((j * 32 + b) * 256 + 2 * (d0 + dw)) * 2 + 1;
            v = (unsigned)f16b(hp[0]) | ((unsigned)f16b(hp[2]) << 16);
          }
          xs[col][dw] = v;
        }
      }
#pragma unroll
      for (int i = 0; i < 8; i++) {
        int f = i * 256 + tid;
        int oo = f >> 5, k = (f >> 4) & 1, dw = f & 15;
        wsm[k][dw][oo] = cwj[(o0 + oo) * 256 + k * 128 + d0 + dw];
      }
      __syncthreads();
#pragma unroll
      for (int g = 0; g < 4; g++) {
        uint4 xv[5];
#pragma unroll
        for (int q = 0; q < 5; q++)
          xv[q] = *(const uint4*)&xs[ty * 4 + q][g * 4];
#pragma unroll
        for (int p = 0; p < 4; p++) {
          unsigned wv0[4], wv1[4];
#pragma unroll
          for (int r = 0; r < 4; r++) {
            wv0[r] = wsm[0][g * 4 + r][tx * 4 + p];
            wv1[r] = wsm[1][g * 4 + r][tx * 4 + p];
          }
#pragma unroll
          for (int q = 0; q < 4; q++) {
            float a = acc[q][p];
            a = fdot2(wv0[0], xv[q].x, a);
            a = fdot2(wv0[1], xv[q].y, a);
            a = fdot2(wv0[2], xv[q].z, a);
            a = fdot2(wv0[3], xv[q].w, a);
            a = fdot2(wv1[0], xv[q + 1].x, a);
            a = fdot2(wv1[1], xv[q + 1].y, a);
            a = fdot2(wv1[2], xv[q + 1].z, a);
            a = fdot2(wv1[3], xv[q + 1].w, a);
            acc[q][p] = a;
          }
        }
      }
    }
  }
#pragma unroll
  for (int p = 0; p < 4; p++) {
    int o = o0 + tx * 4 + p;
    float bias = 0.f;
    for (int j = 0; j < nl; j++) bias += cb[(off + j) * 1024 + o];
#pragma unroll
    for (int q = 0; q < 4; q++) {
      int w = w0 + ty * 4 + q;
      igf[(b * 512 + w) * 1024 + o] = f16b(acc[q][p] + bias);
    }
  }
}

// One WG per batch; 512 threads; lane (s=tid&3, u=tid>>2) computes 8 partial
// row-dots over 1/4 of hx, butterfly-reduced in-wave. 1 barrier/step.
__global__ __launch_bounds__(512)
__attribute__((amdgpu_waves_per_eu(2, 2)))
void rec_kernel(const _Float16* __restrict__ igf, const unsigned* __restrict__ rwp_l,
                const float* __restrict__ rb, const float* __restrict__ aw,
                const float* __restrict__ hidden, const float* __restrict__ context,
                int l, unsigned short* __restrict__ xnext, float* __restrict__ out) {
  __shared__ __align__(16) uint4 w_lds4[16 * 512];          // 128 KB
  __shared__ __align__(16) unsigned short hx_buf[2][256];   // double-buffered raw h
  __shared__ float red[2][8];                                // double-buffered attn partials
  int b = blockIdx.x, tid = threadIdx.x;
  int s = tid & 3, u = tid >> 2, lane = tid & 63, wid = tid >> 6;
  int hh = s & 1;
  int u2 = u + 128 * hh;  // this lane's unit

  // 192 weight dwords -> pinned VGPRs
  unsigned wv[192];
#pragma unroll
  for (int d = 0; d < 192; d++) wv[d] = rwp_l[d * 512 + tid];
#pragma unroll
  for (int d = 0; d < 192; d++) asm volatile("" : "+v"(wv[d]));

  // 64 weight dwords -> LDS (conflict-free b128)
  {
    const uint4* g16 = (const uint4*)(rwp_l + 98304);
#pragma unroll
    for (int c = 0; c < 16; c++) w_lds4[c * 512 + tid] = g16[c * 512 + tid];
  }

  float rb0 = rb[u2], rb1 = rb[256 + u2], rb2 = rb[512 + u2], rb3 = rb[768 + u2];
  float awj = aw[u2];
  float cx = context[((l * 32 + b) * 256 + u2) * 2 + 1];
  if (tid < 256)
    hx_buf[1][tid] = f16b(hidden[(((l + 1) * 32 + b) * 256 + tid) * 2 + 1]);
  float h_prev = 0.f;
  __syncthreads();

  const _Float16* igb = igf + (b * 512) * 1024 + u2;

  for (int t = 0; t < 512; t++) {
    int cur = t & 1, prv = cur ^ 1;
    // ig prefetch (consumed after butterfly, ~1000 cyc later)
    const _Float16* ip = igb + t * 1024;
    float ig0 = (float)ip[0], ig1 = (float)ip[256];
    float ig2 = (float)ip[512], ig3 = (float)ip[768];
    // m = a_(t-1): deferred gating scalar (dot(w, a*h) = a*dot(w,h))
    float m_ = 1.0f;
    if (t) {
      const float* rp = red[prv];
      m_ = sigm(((rp[0] + rp[1]) + (rp[2] + rp[3])) +
                ((rp[4] + rp[5]) + (rp[6] + rp[7])));
    }

    float acc[8] = {};
    const uint4* hq = ((const uint4*)hx_buf[prv]) + 8 * s;
#pragma unroll
    for (int q = 0; q < 6; q++) {
      uint4 h = hq[q];
#pragma unroll
      for (int rl = 0; rl < 8; rl++) {
        acc[rl] = fdot2(wv[rl * 24 + q * 4 + 0], h.x, acc[rl]);
        acc[rl] = fdot2(wv[rl * 24 + q * 4 + 1], h.y, acc[rl]);
        acc[rl] = fdot2(wv[rl * 24 + q * 4 + 2], h.z, acc[rl]);
        acc[rl] = fdot2(wv[rl * 24 + q * 4 + 3], h.w, acc[rl]);
      }
    }
#pragma unroll
    for (int q = 6; q < 8; q++) {
      uint4 h = hq[q];
#pragma unroll
      for (int rl = 0; rl < 8; rl++) {
        uint4 lw = w_lds4[(rl * 2 + (q - 6)) * 512 + tid];
        acc[rl] = fdot2(lw.x, h.x, acc[rl]);
        acc[rl] = fdot2(lw.y, h.y, acc[rl]);
        acc[rl] = fdot2(lw.z, h.z, acc[rl]);
        acc[rl] = fdot2(lw.w, h.w, acc[rl]);
      }
    }
    // butterfly over s (xor 1, then 2): all 4 lanes end with identical sums
    // (IEEE add is commutative, so redundant copies are bit-identical)
#pragma unroll
    for (int rl = 0; rl < 8; rl++) acc[rl] += __shfl_xor(acc[rl], 1);
#pragma unroll
    for (int rl = 0; rl < 8; rl++) acc[rl] += __shfl_xor(acc[rl], 2);

    // this lane's 4 gates (rows g*256 + u2 <-> acc[g*2+hh])
    float di = hh ? acc[1] : acc[0];
    float df = hh ? acc[3] : acc[2];
    float dc = hh ? acc[5] : acc[4];
    float do_ = hh ? acc[7] : acc[6];
    float g_i = ig0 + rb0 + m_ * di;
    float g_f = ig1 + rb1 + m_ * df;
    float g_c = ig2 + rb2 + m_ * dc;
    float g_o = ig3 + rb3 + m_ * do_;
    cx = sigm(g_f) * cx + sigm(g_i) * tanh_(g_c);
    float h_raw = sigm(g_o) * tanh_(cx);

    // attention partial (mask the s=2,3 duplicate copies)
    float part = (s < 2) ? h_raw * awj : 0.f;
#pragma unroll
    for (int sh = 32; sh > 0; sh >>= 1) part += __shfl_xor(part, sh);
    if (lane == 0) red[cur][wid] = part;

    if (s < 2) {
      hx_buf[cur][u2] = f16b(h_raw);  // store RAW h; gating deferred
      if (t) {
        float hg = h_prev * m_;  // gated h of step t-1
        xnext[(b * 512 + (t - 1)) * 256 + u2] = f16b(hg);
        if (t == 511)
          out[(((l + 1) * 32 + b) * 256 + u2) * 2 + 0] = hg;  // x tail w=510
      }
      if (t >= 510)
        out[65536 + ((l * 32 + b) * 256 + u2) * 2 + (t - 510)] = cx;  // nc tail
    }
    if (tid == 0 && t) out[114688 + (l * 32 + b) * 511 + (t - 1)] = m_;  // attn
    h_prev = h_raw;
    __syncthreads();
  }
  // flush last step (ungated)
  if (s < 2) {
    xnext[(b * 512 + 511) * 256 + u2] = f16b(h_prev);
    out[(((l + 1) * 32 + b) * 256 + u2) * 2 + 1] = h_prev;  // x tail w=511
  }
}

extern "C" void kernel_launch(void* const* d_in, const int* in_sizes, int n_in,
                              void* d_out, int out_size, void* d_ws,
                              size_t ws_size, hipStream_t stream) {
  const float* input  = (const float*)d_in[0];
  const float* hidden = (const float*)d_in[1];
  const float* context= (const float*)d_in[2];
  const float* emb_w  = (const float*)d_in[3];
  const float* emb_b  = (const float*)d_in[4];
  const float* conv_w = (const float*)d_in[5];
  const float* conv_b = (const float*)d_in[6];
  const float* rec_w  = (const float*)d_in[7];
  const float* rec_b  = (const float*)d_in[8];
  const float* attn_w = (const float*)d_in[9];
  float* out = (float*)d_out;

  char* ws = (char*)d_ws;
  unsigned short* xf16 = (unsigned short*)ws;                    // 4 x 4,194,304 f16 = 32 MB
  _Float16* igf = (_Float16*)(ws + 33554432);                    // 16,777,216 f16 = 32 MB
  unsigned* rwp = (unsigned*)(ws + 67108864);                    // 1.5 MB
  unsigned* cwp = (unsigned*)(ws + 68681728);                    // 6 MB

  hipLaunchKernelGGL(prep_rw, dim3(1536), dim3(256), 0, stream, rec_w, rwp);
  hipLaunchKernelGGL(prep_cw, dim3(6144), dim3(256), 0, stream, conv_w, cwp);
  hipLaunchKernelGGL(emb_kernel, dim3(8, 4, 32), dim3(256), 0, stream,
                     input, emb_w, emb_b, xf16, out);
  int off = 0;
  for (int l = 0; l < 3; l++) {
    hipLaunchKernelGGL(conv_kernel, dim3(8, 16, 32), dim3(256), 0, stream,
                       xf16, cwp, conv_b, hidden, (unsigned short*)igf, l, off);
    hipLaunchKernelGGL(rec_kernel, dim3(32), dim3(512), 0, stream,
                       igf, rwp + l * 131072, rec_b + l * 1024,
                       attn_w + l * 256, hidden, context, l,
                       xf16 + (l + 1) * 4194304, out);
    off += l + 1;
  }
}